// Round 11
// baseline (233.594 us; speedup 1.0000x reference)
//
#include <hip/hip_runtime.h>
#include <stdint.h>
#include <math.h>

typedef __bf16 bf16;
typedef __attribute__((ext_vector_type(8))) __bf16 bf16x8;
typedef __attribute__((ext_vector_type(4))) __bf16 bf16x4;
typedef __attribute__((ext_vector_type(4))) float f32x4;

#define MFMA_BF16(a, b, c) __builtin_amdgcn_mfma_f32_16x16x32_bf16((a), (b), (c), 0, 0, 0)

#if __has_builtin(__builtin_amdgcn_exp2f)
#define EXP2F __builtin_amdgcn_exp2f
#else
#define EXP2F exp2f
#endif

// scale = 1/sqrt(64) * log2(e): folded into Q so softmax = exp2(s)
#define QSCALE 0.18033688011112042f

// async global->LDS, 16B per lane. LDS dest must be linear in lane order.
__device__ __forceinline__ void gl_lds16(const bf16* g, bf16* l) {
  __builtin_amdgcn_global_load_lds(
      (__attribute__((address_space(1))) unsigned int*)(uintptr_t)(g),
      (__attribute__((address_space(3))) unsigned int*)(l),
      16, 0, 0);
}

// ---------------------------------------------------------------------------
// prep: blocks [0,6144): fp32->bf16 convert of q,k,v (8 elems/thread).
//       blocks [6144,7168): weight transpose+convert dst[n][k]=(bf16)src[k][n].
//       blocks [7168,8192): kpe fp32->bf16 convert (same [h][d][t] layout).
// (bf16 A round-trip kept deliberately: round 5 measured fp32-direct as +50us.)
// ---------------------------------------------------------------------------
__global__ __launch_bounds__(256) void prep(
    const float* __restrict__ q, const float* __restrict__ k,
    const float* __restrict__ v, bf16* __restrict__ qb,
    bf16* __restrict__ kb, bf16* __restrict__ vb,
    const float* __restrict__ W0, const float* __restrict__ W1,
    const float* __restrict__ W2, const float* __restrict__ W3,
    bf16* __restrict__ Wt,
    const float* __restrict__ kpe, bf16* __restrict__ kpeb)
{
  __shared__ float tile[64][65];
  const int tid = threadIdx.x;
  const int bid = blockIdx.x;
  if (bid < 6144) {
    const int z = bid >> 11;            // 2048 blocks per tensor
    const int idx = bid & 2047;
    const float* s = (z == 0) ? q : (z == 1) ? k : v;
    bf16* d = (z == 0) ? qb : (z == 1) ? kb : vb;
    size_t i = ((size_t)idx * 256 + tid) * 8;
    float4 a = *(const float4*)(s + i);
    float4 b = *(const float4*)(s + i + 4);
    bf16x8 o;
    o[0] = (bf16)a.x; o[1] = (bf16)a.y; o[2] = (bf16)a.z; o[3] = (bf16)a.w;
    o[4] = (bf16)b.x; o[5] = (bf16)b.y; o[6] = (bf16)b.z; o[7] = (bf16)b.w;
    *(bf16x8*)(d + i) = o;
  } else if (bid < 7168) {
    const int t = bid - 6144;
    const int z = t >> 8;
    const int rem = t & 255;
    const int r0 = (rem >> 4) * 64, c0 = (rem & 15) * 64;
    const float* src = (z == 0) ? W0 : (z == 1) ? W1 : (z == 2) ? W2 : W3;
    bf16* dst = Wt + (size_t)z * (1024 * 1024);
#pragma unroll
    for (int h = 0; h < 2; ++h) {
      int qq = tid + h * 256;
      int row = qq >> 3, cc = qq & 7;
      float4 a = *(const float4*)(src + (size_t)(r0 + row) * 1024 + c0 + cc * 8);
      float4 b = *(const float4*)(src + (size_t)(r0 + row) * 1024 + c0 + cc * 8 + 4);
      tile[row][cc * 8 + 0] = a.x; tile[row][cc * 8 + 1] = a.y;
      tile[row][cc * 8 + 2] = a.z; tile[row][cc * 8 + 3] = a.w;
      tile[row][cc * 8 + 4] = b.x; tile[row][cc * 8 + 5] = b.y;
      tile[row][cc * 8 + 6] = b.z; tile[row][cc * 8 + 7] = b.w;
    }
    __syncthreads();
#pragma unroll
    for (int h = 0; h < 2; ++h) {
      int qq = tid + h * 256;
      int row = qq >> 3, cc = qq & 7;
      bf16x8 o;
#pragma unroll
      for (int e = 0; e < 8; ++e) o[e] = (bf16)tile[cc * 8 + e][row];
      *(bf16x8*)(dst + (size_t)(c0 + row) * 1024 + r0 + cc * 8) = o;
    }
  } else {
    const int idx = bid - 7168;
    size_t i = ((size_t)idx * 256 + tid) * 8;
    float4 a = *(const float4*)(kpe + i);
    float4 b = *(const float4*)(kpe + i + 4);
    bf16x8 o;
    o[0] = (bf16)a.x; o[1] = (bf16)a.y; o[2] = (bf16)a.z; o[3] = (bf16)a.w;
    o[4] = (bf16)b.x; o[5] = (bf16)b.y; o[6] = (bf16)b.z; o[7] = (bf16)b.w;
    *(bf16x8*)(kpeb + i) = o;
  }
}

// ---------------------------------------------------------------------------
// qkv GEMM, 256x256 tile, 16 waves (1024 threads), BK=32, 3-deep LDS (96 KB,
// 1 block/CU -> 16 waves/CU = 4 waves/SIMD). Round-10 diagnosis: the 8-wave
// variants ran at 2 waves/SIMD and were latency-bound (Occupancy 13.6%,
// MfmaUtil 17%, nothing saturated); this doubles per-SIMD TLP at identical
// tile economics and identical (r8-proven) counted-vmcnt sync structure.
// Per wave: 64x64 output (4x4 frags), 8 ds_read + 16 MFMA per K-step.
// stage = 1 A-chunk + 1 B-chunk per thread -> waits are vmcnt(4)/2/0.
// MODE 0: out[b,h,s,d] bf16 * oscale; MODE 1: += kpe_bf16; MODE 2: V^T.
// ---------------------------------------------------------------------------
template <int MODE>
__device__ __forceinline__ void gemm_body256(
    const bf16* __restrict__ A, const bf16* __restrict__ Wt,
    const float* __restrict__ bias, float oscale,
    const bf16* __restrict__ kpeb, void* __restrict__ out_v,
    bf16* __restrict__ As, bf16* __restrict__ Bs)
{
  const int tid = threadIdx.x;           // 0..1023
  const int w = tid >> 6, lane = tid & 63;
  const int lm = lane & 15, quad = lane >> 4;
  const int wm = w >> 2, wn = w & 3;     // 4 m-waves x 4 n-waves, 64x64 each
  const int lid = blockIdx.x + (blockIdx.y << 2);
  const int xcd = lid & 7, jj = lid >> 3;
  const int m0 = (xcd * 2 + (jj & 1)) * 256;
  const int n0 = (jj >> 1) * 256;

  f32x4 zero4 = {0.f, 0.f, 0.f, 0.f};
  f32x4 acc[4][4];
#pragma unroll
  for (int i = 0; i < 4; ++i)
#pragma unroll
    for (int j = 0; j < 4; ++j) acc[i][j] = zero4;

  auto stage = [&](int buf, int kb) {
    // 1024 chunks each for A and B: 256 rows x 4 chunks, 1/thread each.
    int row = tid >> 2, cs = tid & 3;
    int cc = cs ^ ((row >> 1) & 3);
    gl_lds16(A + (size_t)(m0 + row) * 1024 + kb * 32 + cc * 8,
             As + buf * 8192 + tid * 8);
    gl_lds16(Wt + (size_t)(n0 + row) * 1024 + kb * 32 + cc * 8,
             Bs + buf * 8192 + tid * 8);
  };

  stage(0, 0);
  stage(1, 1);

  int cur = 0;
  for (int kb = 0; kb < 32; ++kb) {
    // counted waits: 3 stages x 2 loads outstanding max; drain oldest 2.
    if (kb < 30) {
      stage((kb + 2) % 3, kb + 2);
      asm volatile("s_waitcnt vmcnt(4)" ::: "memory");
    } else if (kb == 30) {
      asm volatile("s_waitcnt vmcnt(2)" ::: "memory");
    } else {
      asm volatile("s_waitcnt vmcnt(0)" ::: "memory");
    }
    __builtin_amdgcn_s_barrier();        // everyone's stage-kb data in LDS
    asm volatile("" ::: "memory");

    const bf16* Ab = As + cur * 8192;
    const bf16* Bb = Bs + cur * 8192;
    bf16x8 af[4], bfv[4];
#pragma unroll
    for (int i = 0; i < 4; ++i) {
      int row = wm * 64 + i * 16 + lm;
      af[i] = *(const bf16x8*)(Ab + row * 32 + ((quad ^ ((row >> 1) & 3)) * 8));
    }
#pragma unroll
    for (int j = 0; j < 4; ++j) {
      int row = wn * 64 + j * 16 + lm;
      bfv[j] = *(const bf16x8*)(Bb + row * 32 + ((quad ^ ((row >> 1) & 3)) * 8));
    }
#pragma unroll
    for (int i = 0; i < 4; ++i)
#pragma unroll
      for (int j = 0; j < 4; ++j)
        acc[i][j] = MFMA_BF16(af[i], bfv[j], acc[i][j]);

    __builtin_amdgcn_s_barrier();        // all reads of buf[cur] done
    asm volatile("" ::: "memory");
    cur = (cur + 1) == 3 ? 0 : cur + 1;
  }

  // epilogue: C/D layout col=lane&15, row=quad*4+reg
  const int ncol = n0 + wn * 64;
  float bv4[4];
#pragma unroll
  for (int j = 0; j < 4; ++j) bv4[j] = bias[ncol + j * 16 + lm];
#pragma unroll
  for (int i = 0; i < 4; ++i) {
    const int mbase = m0 + wm * 64 + i * 16 + quad * 4;  // 4 consecutive rows
    const int b = mbase >> 11, s = mbase & 2047;         // s..s+3 same batch
#pragma unroll
    for (int j = 0; j < 4; ++j) {
      const int ng = ncol + j * 16 + lm;
      const int hh = ng >> 6, d = ng & 63;
      if (MODE == 2) {
        bf16x4 o;
#pragma unroll
        for (int r = 0; r < 4; ++r) o[r] = (bf16)(acc[i][j][r] + bv4[j]);
        *(bf16x4*)((bf16*)out_v + ((size_t)(b * 16 + hh) * 64 + d) * 2048 + s) = o;
      } else if (MODE == 1) {
        bf16x4 p4 = *(const bf16x4*)(kpeb + ((size_t)(hh * 64 + d)) * 2048 + s);
#pragma unroll
        for (int r = 0; r < 4; ++r) {
          float val = acc[i][j][r] + bv4[j] + (float)p4[r];
          ((bf16*)out_v)[(((size_t)(b * 16 + hh)) * 2048 + (s + r)) * 64 + d] =
              (bf16)val;
        }
      } else {  // MODE 0
#pragma unroll
        for (int r = 0; r < 4; ++r) {
          float val = acc[i][j][r] + bv4[j];
          ((bf16*)out_v)[(((size_t)(b * 16 + hh)) * 2048 + (s + r)) * 64 + d] =
              (bf16)(val * oscale);
        }
      }
    }
  }
}

__global__ __launch_bounds__(1024, 4) void qkv_gemm(
    const bf16* __restrict__ qb, const bf16* __restrict__ kb, const bf16* __restrict__ vb,
    const bf16* __restrict__ Wt, const float* __restrict__ biq,
    const float* __restrict__ bik, const float* __restrict__ biv,
    const bf16* __restrict__ kpeb,
    bf16* __restrict__ Qs, bf16* __restrict__ Ks, bf16* __restrict__ Vts)
{
  __shared__ __align__(16) bf16 As[3 * 256 * 32];  // 48 KB, 3-deep, BK=32
  __shared__ __align__(16) bf16 Bs[3 * 256 * 32];  // 48 KB, 3-deep, BK=32
  const int z = blockIdx.z;
  if (z == 0) {
    gemm_body256<0>(qb, Wt, biq, QSCALE, nullptr, Qs, As, Bs);
  } else if (z == 1) {
    gemm_body256<1>(kb, Wt + (size_t)1 * 1024 * 1024, bik, 1.f, kpeb, Ks, As, Bs);
  } else {
    gemm_body256<2>(vb, Wt + (size_t)2 * 1024 * 1024, biv, 1.f, nullptr, Vts, As, Bs);
  }
}

// ---------------------------------------------------------------------------
// out GEMM (128² tile, 4 waves, dist-2 pipeline + XCD swizzle — round-7 form).
// ---------------------------------------------------------------------------
__global__ __launch_bounds__(256) void out_gemm(
    const bf16* __restrict__ A, const bf16* __restrict__ Wt,
    const float* __restrict__ bias, float* __restrict__ out)
{
  __shared__ __align__(16) bf16 As[3 * 128 * 32];
  __shared__ __align__(16) bf16 Bs[3 * 128 * 32];
  const int tid = threadIdx.x;
  const int w = tid >> 6, lane = tid & 63;
  const int lm = lane & 15, quad = lane >> 4;
  const int wr = w >> 1, wc = w & 1;
  const int lid = blockIdx.x + (blockIdx.y << 3);
  const int xcd = lid & 7, j = lid >> 3;
  const int m0 = (xcd * 4 + (j & 3)) * 128;
  const int n0 = (j >> 2) * 128;

  f32x4 zero4 = {0.f, 0.f, 0.f, 0.f};
  f32x4 acc[4][4];
#pragma unroll
  for (int i = 0; i < 4; ++i)
#pragma unroll
    for (int jj = 0; jj < 4; ++jj) acc[i][jj] = zero4;

  auto stage = [&](int buf, int kb) {
#pragma unroll
    for (int h = 0; h < 2; ++h) {
      int qq = tid + h * 256;
      int row = qq >> 2, cs = qq & 3;
      int cc = cs ^ ((row >> 1) & 3);
      gl_lds16(A + (size_t)(m0 + row) * 1024 + kb * 32 + cc * 8,
               As + buf * 4096 + qq * 8);
      gl_lds16(Wt + (size_t)(n0 + row) * 1024 + kb * 32 + cc * 8,
               Bs + buf * 4096 + qq * 8);
    }
  };

  stage(0, 0);
  stage(1, 1);

  int cur = 0;
  for (int kb = 0; kb < 32; ++kb) {
    if (kb < 30) {
      stage((kb + 2) % 3, kb + 2);
      asm volatile("s_waitcnt vmcnt(8)" ::: "memory");
    } else if (kb == 30) {
      asm volatile("s_waitcnt vmcnt(4)" ::: "memory");
    } else {
      asm volatile("s_waitcnt vmcnt(0)" ::: "memory");
    }
    __builtin_amdgcn_s_barrier();
    asm volatile("" ::: "memory");

    const bf16* Ab = As + cur * 4096;
    const bf16* Bb = Bs + cur * 4096;
    bf16x8 af[4], bfv[4];
#pragma unroll
    for (int i = 0; i < 4; ++i) {
      int row = wr * 64 + i * 16 + lm;
      af[i] = *(const bf16x8*)(Ab + row * 32 + ((quad ^ ((row >> 1) & 3)) * 8));
    }
#pragma unroll
    for (int jj = 0; jj < 4; ++jj) {
      int row = wc * 64 + jj * 16 + lm;
      bfv[jj] = *(const bf16x8*)(Bb + row * 32 + ((quad ^ ((row >> 1) & 3)) * 8));
    }
#pragma unroll
    for (int i = 0; i < 4; ++i)
#pragma unroll
      for (int jj = 0; jj < 4; ++jj)
        acc[i][jj] = MFMA_BF16(af[i], bfv[jj], acc[i][jj]);

    __builtin_amdgcn_s_barrier();
    asm volatile("" ::: "memory");
    cur = (cur + 1) == 3 ? 0 : cur + 1;
  }

  const int ncol = n0 + wc * 64;
  float bv4[4];
#pragma unroll
  for (int jj = 0; jj < 4; ++jj) bv4[jj] = bias[ncol + jj * 16 + lm];
#pragma unroll
  for (int i = 0; i < 4; ++i) {
    const int mbase = m0 + wr * 64 + i * 16 + quad * 4;
#pragma unroll
    for (int jj = 0; jj < 4; ++jj) {
      const int ng = ncol + jj * 16 + lm;
#pragma unroll
      for (int r = 0; r < 4; ++r) {
        out[(size_t)(mbase + r) * 1024 + ng] = acc[i][jj][r] + bv4[jj];
      }
    }
  }
}

// ---------------------------------------------------------------------------
// Flash attention (round-8 form, best measured 54.1us): transposed-score
// no-max softmax, Br=128 (8 waves x 16 queries), Bc=64, K/V dbuf
// 1-barrier/iter, Qt/Ps LDS union (50 KB, 3 blocks/CU), setprio around MFMA,
// XCD-aware 1D grid (id%8=XCD, 4 bh each).
// ---------------------------------------------------------------------------
__global__ __launch_bounds__(512) void flash_attn(
    const bf16* __restrict__ Q, const bf16* __restrict__ K,
    const bf16* __restrict__ Vt, bf16* __restrict__ O)
{
  __shared__ __align__(16) bf16 QtPs[128 * 72];  // Qt staging (128*64) / Ps
  __shared__ __align__(16) bf16 Kt[2][64 * 64];
  __shared__ __align__(16) bf16 Vs[2][64 * 64];
  bf16* Ps = QtPs;

  const int tid = threadIdx.x;
  const int w = tid >> 6, lane = tid & 63;
  const int lm = lane & 15, quad = lane >> 4;
  const int id = blockIdx.x;
  const int xcd = id & 7, j = id >> 3;
  const int bh = xcd * 4 + (j & 3);
  const int s0 = (j >> 2) * 128;
  const size_t qkbase = (size_t)bh * (2048 * 64);
  const size_t vbase = (size_t)bh * (64 * 2048);

#pragma unroll
  for (int h = 0; h < 2; ++h) {
    int qq = tid + h * 512;
    int row = qq >> 3, cs = qq & 7;
    int cc = cs ^ (row & 7);
    gl_lds16(Q + qkbase + (size_t)(s0 + row) * 64 + cc * 8, QtPs + qq * 8);
  }
  {
    int row = tid >> 3, cs = tid & 7;
    int cc = cs ^ (row & 7);
    gl_lds16(K + qkbase + (size_t)row * 64 + cc * 8, Kt[0] + tid * 8);
    gl_lds16(Vt + vbase + (size_t)row * 2048 + cc * 8, Vs[0] + tid * 8);
  }
  __syncthreads();

  bf16x8 qa0, qa1;
  {
    int row = w * 16 + lm;
    qa0 = *(const bf16x8*)(QtPs + row * 64 + ((quad ^ (row & 7)) * 8));
    qa1 = *(const bf16x8*)(QtPs + row * 64 + (((quad + 4) ^ (row & 7)) * 8));
  }
  __syncthreads();  // qa reads done before Ps overwrites the union

  f32x4 zero4 = {0.f, 0.f, 0.f, 0.f};
  float l_part = 0.f;
  f32x4 oacc[4];
#pragma unroll
  for (int dt = 0; dt < 4; ++dt) oacc[dt] = zero4;

  const int prow = (w * 16 + lm) * 72;

  for (int kt = 0; kt < 32; ++kt) {
    const int cur = kt & 1;
    if (kt < 31) {
      const int t1 = (kt + 1) * 64;
      int row = tid >> 3, cs = tid & 7;
      int cc = cs ^ (row & 7);
      gl_lds16(K + qkbase + (size_t)(t1 + row) * 64 + cc * 8, Kt[cur ^ 1] + tid * 8);
      gl_lds16(Vt + vbase + (size_t)row * 2048 + t1 + cc * 8, Vs[cur ^ 1] + tid * 8);
    }

#pragma unroll
    for (int c = 0; c < 4; ++c) {
      int row = c * 16 + lm;
      bf16x8 kb0 = *(const bf16x8*)(Kt[cur] + row * 64 + ((quad ^ (row & 7)) * 8));
      bf16x8 kb1 = *(const bf16x8*)(Kt[cur] + row * 64 + (((quad + 4) ^ (row & 7)) * 8));
      __builtin_amdgcn_s_setprio(1);
      f32x4 z = MFMA_BF16(kb0, qa0, zero4);
      f32x4 st = MFMA_BF16(kb1, qa1, z);
      __builtin_amdgcn_s_setprio(0);
      bf16x4 pk;
#pragma unroll
      for (int r = 0; r < 4; ++r) {
        float p = EXP2F(st[r]);
        l_part += p;
        pk[r] = (bf16)p;
      }
      *(bf16x4*)(Ps + prow + c * 16 + quad * 4) = pk;
    }

    bf16x8 pa0 = *(const bf16x8*)(Ps + prow + quad * 8);
    bf16x8 pa1 = *(const bf16x8*)(Ps + prow + 32 + quad * 8);
#pragma unroll
    for (int dt = 0; dt < 4; ++dt) {
      int row = dt * 16 + lm;
      bf16x8 va0 = *(const bf16x8*)(Vs[cur] + row * 64 + ((quad ^ (row & 7)) * 8));
      bf16x8 va1 = *(const bf16x8*)(Vs[cur] + row * 64 + (((quad + 4) ^ (row & 7)) * 8));
      __builtin_amdgcn_s_setprio(1);
      oacc[dt] = MFMA_BF16(va0, pa0, oacc[dt]);
      oacc[dt] = MFMA_BF16(va1, pa1, oacc[dt]);
      __builtin_amdgcn_s_setprio(0);
    }

    __syncthreads();
  }

  float l = l_part;
  l += __shfl_xor(l, 16, 64);
  l += __shfl_xor(l, 32, 64);
  float inv = 1.f / l;
#pragma unroll
  for (int dt = 0; dt < 4; ++dt)
#pragma unroll
    for (int r = 0; r < 4; ++r)
      Ps[prow + dt * 16 + quad * 4 + r] = (bf16)(oacc[dt][r] * inv);

  const int b = bh >> 4, hh = bh & 15;
  const int srow = s0 + w * 16 + lm;
  const size_t ob = ((size_t)(b * 2048 + srow)) * 1024 + hh * 64;
#pragma unroll
  for (int half = 0; half < 2; ++half) {
    bf16x8 ov = *(const bf16x8*)(Ps + prow + (half * 4 + quad) * 8);
    *(bf16x8*)(O + ob + (half * 4 + quad) * 8) = ov;
  }
}

// ---------------------------------------------------------------------------
extern "C" void kernel_launch(void* const* d_in, const int* in_sizes, int n_in,
                              void* d_out, int out_size, void* d_ws, size_t ws_size,
                              hipStream_t stream) {
  (void)in_sizes; (void)n_in; (void)out_size; (void)ws_size;
  const float* q   = (const float*)d_in[0];
  const float* k   = (const float*)d_in[1];
  const float* v   = (const float*)d_in[2];
  const float* kpe = (const float*)d_in[3];
  const float* Wq  = (const float*)d_in[4];
  const float* bq  = (const float*)d_in[5];
  const float* Wk  = (const float*)d_in[6];
  const float* bk  = (const float*)d_in[7];
  const float* Wv  = (const float*)d_in[8];
  const float* bv  = (const float*)d_in[9];
  const float* Wo  = (const float*)d_in[10];
  const float* bo  = (const float*)d_in[11];

  const size_t NT = 4u * 1024 * 1024;  // 4M elems per [4096,1024] tensor
  bf16* ws  = (bf16*)d_ws;
  bf16* Wt  = ws;            // 4 x 1M elems (bf16 W^T for Wq,Wk,Wv,Wo)
  bf16* qb  = Wt + NT;       // bf16 copies of q,k,v
  bf16* kb  = qb + NT;
  bf16* vb  = kb + NT;
  bf16* Qs  = vb + NT;       // [bh][s][d], pre-scaled
  bf16* Ks  = Qs + NT;       // K_eff = K + kpe^T  [bh][t][d]  (fused in GEMM)
  bf16* Vts = Ks + NT;       // V^T  [bh][d][t]               (fused in GEMM)
  bf16* Oa  = Vts + NT;      // attn out [b][s][h*64+d]
  bf16* kpeb = Oa;           // bf16 kpe [h][d][t]: aliases Oa — consumed by
                             // qkv_gemm before flash_attn writes O there.

  prep<<<dim3(8192), 256, 0, stream>>>(q, k, v, qb, kb, vb, Wq, Wk, Wv, Wo, Wt,
                                       kpe, kpeb);
  qkv_gemm<<<dim3(4, 16, 3), 1024, 0, stream>>>(qb, kb, vb, Wt, bq, bk, bv, kpeb,
                                                Qs, Ks, Vts);
  flash_attn<<<dim3(512), 512, 0, stream>>>(Qs, Ks, Vts, Oa);
  out_gemm<<<dim3(8, 32), 256, 0, stream>>>(Oa, Wt + 3u * 1024 * 1024, bo,
                                            (float*)d_out);
}